// Round 1
// baseline (2007.014 us; speedup 1.0000x reference)
//
#include <hip/hip_runtime.h>
#include <hip/hip_bf16.h>

#define N_NODES 100000
#define N_EDGES 1600000
#define IN_DIM 8
#define D 50
#define D2 100
#define NTASK 112
#define BN_EPS 1e-5f

#define NB1 64   // nodes per block in gemm1
#define NB2 32   // nodes per block in gemm2

// h[n,j] = node_feats[n,:] @ node_W + node_b
__global__ void node_enc_kernel(const float* __restrict__ nf, const float* __restrict__ nW,
                                const float* __restrict__ nb, float* __restrict__ h) {
    __shared__ float sW[IN_DIM * D];
    __shared__ float sb[D];
    for (int i = threadIdx.x; i < IN_DIM * D; i += blockDim.x) sW[i] = nW[i];
    for (int i = threadIdx.x; i < D; i += blockDim.x) sb[i] = nb[i];
    __syncthreads();
    int t = blockIdx.x * blockDim.x + threadIdx.x;
    if (t >= N_NODES * D) return;
    int n = t / D, j = t % D;
    float v = sb[j];
#pragma unroll
    for (int k = 0; k < IN_DIM; k++) v += nf[n * IN_DIM + k] * sW[k * D + j];
    h[t] = v;
}

__global__ void deg_kernel(const int* __restrict__ dst, float* __restrict__ invd) {
    int e = blockIdx.x * blockDim.x + threadIdx.x;
    if (e < N_EDGES) atomicAdd(&invd[dst[e]], 1.0f);
}

__global__ void invd_fin_kernel(float* __restrict__ invd) {
    int n = blockIdx.x * blockDim.x + threadIdx.x;
    if (n >= N_NODES) return;
    float dg = invd[n];
    invd[n] = (dg > 0.0f) ? (1.0f / dg) : 0.0f;
}

// per (edge, d): agg[dst*D+d] += h[src*D+d] + (edge_feats[e,:] @ edge_W[:,d] + edge_b[d])
__global__ void scatter_kernel(const int* __restrict__ src, const int* __restrict__ dst,
                               const float* __restrict__ ef, const float* __restrict__ eW,
                               const float* __restrict__ eb, const float* __restrict__ h,
                               float* __restrict__ agg) {
    __shared__ float sW[IN_DIM * D];
    __shared__ float sb[D];
    for (int i = threadIdx.x; i < IN_DIM * D; i += blockDim.x) sW[i] = eW[i];
    for (int i = threadIdx.x; i < D; i += blockDim.x) sb[i] = eb[i];
    __syncthreads();
    int t = blockIdx.x * blockDim.x + threadIdx.x;
    if (t >= N_EDGES * D) return;
    int e = t / D, d = t % D;
    int s = src[e], dn = dst[e];
    float v = sb[d];
#pragma unroll
    for (int k = 0; k < IN_DIM; k++) v += ef[e * IN_DIM + k] * sW[k * D + d];
    v += h[s * D + d];
    atomicAdd(&agg[dn * D + d], v);
}

// combine (h = (1+eps)*h + agg*invd), y1 = hnew @ W1 + b1, accumulate BN sums
__global__ __launch_bounds__(256) void gemm1_kernel(
    const float* __restrict__ h, const float* __restrict__ agg, const float* __restrict__ invd,
    const float* __restrict__ W1, const float* __restrict__ b1, const float* __restrict__ epsArr,
    int layer, float* __restrict__ y1, float* __restrict__ s1, float* __restrict__ q1) {
    __shared__ float sh[NB1 * D];    // staged hnew
    __shared__ float sW[D * D2];
    __shared__ float sb[D2];
    __shared__ float ssum[D2], ssq[D2];
    float epsv = 1.0f + epsArr[layer];
    int n0 = blockIdx.x * NB1;
    for (int i = threadIdx.x; i < D * D2; i += 256) sW[i] = W1[i];
    for (int i = threadIdx.x; i < D2; i += 256) { sb[i] = b1[i]; ssum[i] = 0.0f; ssq[i] = 0.0f; }
    for (int i = threadIdx.x; i < NB1 * D; i += 256) {
        int n = i / D, d = i % D;
        int g = n0 + n;
        sh[i] = (g < N_NODES) ? (epsv * h[g * D + d] + agg[g * D + d] * invd[g]) : 0.0f;
    }
    __syncthreads();
    for (int idx = threadIdx.x; idx < NB1 * D2; idx += 256) {
        int n = idx / D2, j = idx % D2;
        int g = n0 + n;
        if (g < N_NODES) {
            float v = sb[j];
#pragma unroll
            for (int d = 0; d < D; d++) v += sh[n * D + d] * sW[d * D2 + j];
            y1[g * D2 + j] = v;
            atomicAdd(&ssum[j], v);
            atomicAdd(&ssq[j], v * v);
        }
    }
    __syncthreads();
    for (int j = threadIdx.x; j < D2; j += 256) {
        atomicAdd(&s1[j], ssum[j]);
        atomicAdd(&q1[j], ssq[j]);
    }
}

// a = gamma*rsqrt(var+eps); c = beta - mu*a
__global__ void bn_fin_kernel(const float* __restrict__ s, const float* __restrict__ q,
                              const float* __restrict__ gamma, const float* __restrict__ beta,
                              float* __restrict__ a, float* __restrict__ c, int dim) {
    int j = threadIdx.x;
    if (j >= dim) return;
    float inv_n = 1.0f / (float)N_NODES;
    float mu = s[j] * inv_n;
    float var = q[j] * inv_n - mu * mu;
    float rs = rsqrtf(var + BN_EPS);
    float av = gamma[j] * rs;
    a[j] = av;
    c[j] = beta[j] - mu * av;
}

// z = relu(y1*a1+c1); y2 = z @ W2 + b2; accumulate BN sums
__global__ __launch_bounds__(256) void gemm2_kernel(
    const float* __restrict__ y1, const float* __restrict__ a1, const float* __restrict__ c1,
    const float* __restrict__ W2, const float* __restrict__ b2,
    float* __restrict__ y2, float* __restrict__ s2, float* __restrict__ q2) {
    __shared__ float sz[NB2 * D2];   // staged relu(bn(y1))
    __shared__ float sW[D2 * D];
    __shared__ float sa[D2], sc[D2], sb[D];
    __shared__ float ssum[D], ssq[D];
    int n0 = blockIdx.x * NB2;
    for (int i = threadIdx.x; i < D2 * D; i += 256) sW[i] = W2[i];
    for (int i = threadIdx.x; i < D2; i += 256) { sa[i] = a1[i]; sc[i] = c1[i]; }
    for (int i = threadIdx.x; i < D; i += 256) { sb[i] = b2[i]; ssum[i] = 0.0f; ssq[i] = 0.0f; }
    __syncthreads();
    for (int i = threadIdx.x; i < NB2 * D2; i += 256) {
        int n = i / D2, d = i % D2;
        int g = n0 + n;
        float z = 0.0f;
        if (g < N_NODES) {
            z = y1[g * D2 + d] * sa[d] + sc[d];
            z = fmaxf(z, 0.0f);
        }
        sz[i] = z;
    }
    __syncthreads();
    for (int idx = threadIdx.x; idx < NB2 * D; idx += 256) {
        int n = idx / D, j = idx % D;
        int g = n0 + n;
        if (g < N_NODES) {
            float v = sb[j];
#pragma unroll
            for (int d = 0; d < D2; d++) v += sz[n * D2 + d] * sW[d * D + j];
            y2[g * D + j] = v;
            atomicAdd(&ssum[j], v);
            atomicAdd(&ssq[j], v * v);
        }
    }
    __syncthreads();
    for (int j = threadIdx.x; j < D; j += 256) {
        atomicAdd(&s2[j], ssum[j]);
        atomicAdd(&q2[j], ssq[j]);
    }
}

// h = relu(y2*a2+c2)
__global__ void apply2_kernel(const float* __restrict__ y2, const float* __restrict__ a2,
                              const float* __restrict__ c2, float* __restrict__ h) {
    int t = blockIdx.x * blockDim.x + threadIdx.x;
    if (t >= N_NODES * D) return;
    int j = t % D;
    h[t] = fmaxf(y2[t] * a2[j] + c2[j], 0.0f);
}

// out = h @ pred_W + pred_b
__global__ void pred_kernel(const float* __restrict__ h, const float* __restrict__ pW,
                            const float* __restrict__ pb, float* __restrict__ out) {
    __shared__ float sW[D * NTASK];
    __shared__ float sb[NTASK];
    for (int i = threadIdx.x; i < D * NTASK; i += blockDim.x) sW[i] = pW[i];
    for (int i = threadIdx.x; i < NTASK; i += blockDim.x) sb[i] = pb[i];
    __syncthreads();
    int t = blockIdx.x * blockDim.x + threadIdx.x;
    if (t >= N_NODES * NTASK) return;
    int n = t / NTASK, j = t % NTASK;
    float v = sb[j];
#pragma unroll
    for (int d = 0; d < D; d++) v += h[n * D + d] * sW[d * NTASK + j];
    out[t] = v;
}

extern "C" void kernel_launch(void* const* d_in, const int* in_sizes, int n_in,
                              void* d_out, int out_size, void* d_ws, size_t ws_size,
                              hipStream_t stream) {
    const int*   src        = (const int*)d_in[0];
    const int*   dst        = (const int*)d_in[1];
    const float* node_feats = (const float*)d_in[2];
    const float* edge_feats = (const float*)d_in[3];
    const float* node_W     = (const float*)d_in[4];
    const float* node_b     = (const float*)d_in[5];
    const float* edge_W     = (const float*)d_in[6];
    const float* edge_b     = (const float*)d_in[7];
    const float* epsArr     = (const float*)d_in[8];
    const float* W1         = (const float*)d_in[9];
    const float* b1         = (const float*)d_in[10];
    const float* g1         = (const float*)d_in[11];
    const float* be1        = (const float*)d_in[12];
    const float* W2         = (const float*)d_in[13];
    const float* b2         = (const float*)d_in[14];
    const float* g2         = (const float*)d_in[15];
    const float* be2        = (const float*)d_in[16];
    const float* pred_W     = (const float*)d_in[17];
    const float* pred_b     = (const float*)d_in[18];
    float* out = (float*)d_out;

    // workspace layout (floats): h[N*D], agg[N*D], invd[N], stats[768]
    float* ws   = (float*)d_ws;
    float* h    = ws;
    float* agg  = h + (size_t)N_NODES * D;
    float* invd = agg + (size_t)N_NODES * D;
    float* st   = invd + N_NODES;
    float* s1 = st, *q1 = st + 128, *s2 = st + 256, *q2 = st + 320;
    float* a1 = st + 384, *c1 = st + 512, *a2 = st + 640, *c2 = st + 704;

    // y1 lives in d_out (40MB fits in 44.8MB out buffer; fully overwritten by pred at end)
    float* y1 = out;

    hipMemsetAsync(invd, 0, N_NODES * sizeof(float), stream);
    node_enc_kernel<<<(N_NODES * D + 255) / 256, 256, 0, stream>>>(node_feats, node_W, node_b, h);
    deg_kernel<<<(N_EDGES + 255) / 256, 256, 0, stream>>>(dst, invd);
    invd_fin_kernel<<<(N_NODES + 255) / 256, 256, 0, stream>>>(invd);

    for (int layer = 0; layer < 2; layer++) {
        hipMemsetAsync(agg, 0, (size_t)N_NODES * D * sizeof(float), stream);
        hipMemsetAsync(st, 0, 384 * sizeof(float), stream);
        scatter_kernel<<<(N_EDGES * D + 255) / 256, 256, 0, stream>>>(
            src, dst, edge_feats, edge_W, edge_b, h, agg);
        gemm1_kernel<<<(N_NODES + NB1 - 1) / NB1, 256, 0, stream>>>(
            h, agg, invd, W1 + layer * D * D2, b1 + layer * D2, epsArr, layer, y1, s1, q1);
        bn_fin_kernel<<<1, 128, 0, stream>>>(s1, q1, g1 + layer * D2, be1 + layer * D2, a1, c1, D2);
        gemm2_kernel<<<(N_NODES + NB2 - 1) / NB2, 256, 0, stream>>>(
            y1, a1, c1, W2 + layer * D2 * D, b2 + layer * D, agg, s2, q2);
        bn_fin_kernel<<<1, 128, 0, stream>>>(s2, q2, g2 + layer * D, be2 + layer * D, a2, c2, D);
        apply2_kernel<<<(N_NODES * D + 255) / 256, 256, 0, stream>>>(agg, a2, c2, h);
    }
    pred_kernel<<<(N_NODES * NTASK + 255) / 256, 256, 0, stream>>>(h, pred_W, pred_b, out);
}

// Round 2
// 1177.060 us; speedup vs baseline: 1.7051x; 1.7051x over previous
//
#include <hip/hip_runtime.h>
#include <hip/hip_bf16.h>

#define N_NODES 100000
#define N_EDGES 1600000
#define IN_DIM 8
#define D 50
#define D2 100
#define NTASK 112
#define BN_EPS 1e-5f
#define NBLK ((N_NODES + 255) / 256)   // 391 scan blocks

// ---------------------------------------------------------------------------
// node encoder: h[n,j] = nf[n,:] @ nW + nb   (block = 256, 40 nodes/block)
// ---------------------------------------------------------------------------
#define NE_NODES 40
__global__ __launch_bounds__(256) void node_enc_kernel(
    const float* __restrict__ nf, const float* __restrict__ nW,
    const float* __restrict__ nb, float* __restrict__ h) {
    __shared__ float sW[IN_DIM * D];
    __shared__ float sb[D];
    __shared__ float snf[NE_NODES * IN_DIM];
    int t = threadIdx.x;
    int n0 = blockIdx.x * NE_NODES;
    for (int i = t; i < IN_DIM * D; i += 256) sW[i] = nW[i];
    for (int i = t; i < D; i += 256) sb[i] = nb[i];
    for (int i = t; i < NE_NODES * IN_DIM; i += 256) {
        int g = n0 * IN_DIM + i;
        snf[i] = (g < N_NODES * IN_DIM) ? nf[g] : 0.0f;
    }
    __syncthreads();
    int j = t % D, grp = t / D;       // grps 0..4 active (250 threads), 6 idle
    if (grp < 5) {
        for (int n = grp * 8; n < grp * 8 + 8; n++) {
            int g = n0 + n;
            if (g >= N_NODES) break;
            float v = sb[j];
#pragma unroll
            for (int k = 0; k < IN_DIM; k++) v += snf[n * IN_DIM + k] * sW[k * D + j];
            h[(size_t)g * D + j] = v;
        }
    }
}

// ---------------------------------------------------------------------------
// CSR build: degree count -> two-level exclusive scan -> adjacency fill
// ---------------------------------------------------------------------------
__global__ void k_deg(const int* __restrict__ dst, int* __restrict__ degi) {
    int e = blockIdx.x * blockDim.x + threadIdx.x;
    if (e < N_EDGES) atomicAdd(&degi[dst[e]], 1);
}

__global__ void k_bsum(const int* __restrict__ degi, int* __restrict__ bsum) {
    __shared__ int lds[256];
    int t = threadIdx.x, i = blockIdx.x * 256 + t;
    lds[t] = (i < N_NODES) ? degi[i] : 0;
    __syncthreads();
    for (int s = 128; s > 0; s >>= 1) {
        if (t < s) lds[t] += lds[t + s];
        __syncthreads();
    }
    if (t == 0) bsum[blockIdx.x] = lds[0];
}

__global__ void k_bscan(const int* __restrict__ bsum, int* __restrict__ bpre) {
    __shared__ int lds[512];
    int t = threadIdx.x;
    int x = (t < NBLK) ? bsum[t] : 0;
    lds[t] = x;
    __syncthreads();
    int acc = x;
    for (int s = 1; s < 512; s <<= 1) {
        int add = (t >= s) ? lds[t - s] : 0;
        __syncthreads();
        acc += add;
        lds[t] = acc;
        __syncthreads();
    }
    if (t < NBLK) bpre[t] = acc - x;   // exclusive
}

__global__ void k_off(const int* __restrict__ degi, const int* __restrict__ bpre,
                      int* __restrict__ off, int* __restrict__ cursor,
                      float* __restrict__ invd) {
    __shared__ int lds[256];
    int t = threadIdx.x, i = blockIdx.x * 256 + t;
    int dv = (i < N_NODES) ? degi[i] : 0;
    lds[t] = dv;
    __syncthreads();
    int acc = dv;
    for (int s = 1; s < 256; s <<= 1) {
        int add = (t >= s) ? lds[t - s] : 0;
        __syncthreads();
        acc += add;
        lds[t] = acc;
        __syncthreads();
    }
    int excl = acc - dv + bpre[blockIdx.x];
    if (i < N_NODES) {
        off[i] = excl;
        cursor[i] = excl;
        invd[i] = (dv > 0) ? (1.0f / (float)dv) : 0.0f;
    }
    if (i == 0) off[N_NODES] = N_EDGES;
}

__global__ void k_fill(const int* __restrict__ src, const int* __restrict__ dst,
                       int* __restrict__ cursor, int2* __restrict__ adj) {
    int e = blockIdx.x * blockDim.x + threadIdx.x;
    if (e >= N_EDGES) return;
    int d = dst[e];
    int pos = atomicAdd(&cursor[d], 1);
    adj[pos] = make_int2(src[e], e);
}

// ---------------------------------------------------------------------------
// per-wave per-node gather + eps-combine:
//   hnew[n,d] = (1+eps)*h[n,d] + invd[n] * sum_{e: dst=n} ( h[src_e,d] + eE[e,d] )
// block = 256 = 4 waves, one node per wave, lane = feature dim
// ---------------------------------------------------------------------------
__global__ __launch_bounds__(256) void gather_kernel(
    const int* __restrict__ off, const int2* __restrict__ adj,
    const float* __restrict__ ef, const float* __restrict__ eW,
    const float* __restrict__ eb, const float* __restrict__ h,
    const float* __restrict__ invd, const float* __restrict__ epsArr, int layer,
    float* __restrict__ hnew) {
    __shared__ float sW[IN_DIM * D];
    __shared__ float sB[D];
    int t = threadIdx.x;
    for (int i = t; i < IN_DIM * D; i += 256) sW[i] = eW[i];
    for (int i = t; i < D; i += 256) sB[i] = eb[i];
    __syncthreads();
    int lane = t & 63, wv = t >> 6;
    int n = blockIdx.x * 4 + wv;
    if (n >= N_NODES) return;
    int dd = (lane < D) ? lane : (D - 1);   // clamp to stay convergent
    const float4* ef4 = (const float4*)ef;
    int p = off[n], pend = off[n + 1];
    float acc = 0.0f;
    int2 a_next;
    if (p < pend) a_next = adj[p];
    while (p < pend) {
        int2 a = a_next;
        if (p + 1 < pend) a_next = adj[p + 1];
        float hv = h[(size_t)a.x * D + dd];            // coalesced 200B row
        float4 f0 = ef4[(size_t)a.y * 2];              // broadcast 32B
        float4 f1 = ef4[(size_t)a.y * 2 + 1];
        float ev = sB[dd];
        ev += f0.x * sW[0 * D + dd];
        ev += f0.y * sW[1 * D + dd];
        ev += f0.z * sW[2 * D + dd];
        ev += f0.w * sW[3 * D + dd];
        ev += f1.x * sW[4 * D + dd];
        ev += f1.y * sW[5 * D + dd];
        ev += f1.z * sW[6 * D + dd];
        ev += f1.w * sW[7 * D + dd];
        acc += hv + ev;
        p++;
    }
    if (lane < D) {
        float epsv = 1.0f + epsArr[layer];
        hnew[(size_t)n * D + lane] = epsv * h[(size_t)n * D + lane] + acc * invd[n];
    }
}

// ---------------------------------------------------------------------------
// gemm1: y1 = hnew @ W1 + b1, BN sums via register accumulation.
// block = 256: j = t%100, grp = t/100 (grps 0,1 -> 32 nodes each; 56 idle)
// ---------------------------------------------------------------------------
#define G1N 64
__global__ __launch_bounds__(256) void gemm1_new_kernel(
    const float* __restrict__ hnew, const float* __restrict__ W1,
    const float* __restrict__ b1, float* __restrict__ y1,
    float* __restrict__ s1g, float* __restrict__ q1g) {
    __shared__ float sh[G1N * D];       // 12.8 KB
    __shared__ float sW[D * D2];        // 20 KB
    __shared__ float sb[D2];
    __shared__ float sp[2 * 104], qp[2 * 104];
    int t = threadIdx.x, n0 = blockIdx.x * G1N;
    for (int i = t; i < D * D2; i += 256) sW[i] = W1[i];
    for (int i = t; i < D2; i += 256) sb[i] = b1[i];
    for (int i = t; i < G1N * D; i += 256) {
        int g = n0 * D + i;
        sh[i] = (g < N_NODES * D) ? hnew[g] : 0.0f;
    }
    __syncthreads();
    int j = t % D2, grp = t / D2;
    if (grp < 2) {
        float s = 0.0f, q = 0.0f;
        for (int n = grp * 32; n < grp * 32 + 32; n++) {
            int g = n0 + n;
            if (g >= N_NODES) break;
            const float* r = &sh[n * D];
            float v = sb[j];
#pragma unroll
            for (int d = 0; d < D; d++) v += r[d] * sW[d * D2 + j];
            y1[(size_t)g * D2 + j] = v;
            s += v;
            q += v * v;
        }
        sp[grp * 104 + j] = s;
        qp[grp * 104 + j] = q;
    }
    __syncthreads();
    if (t < D2) {
        atomicAdd(&s1g[t], sp[t] + sp[104 + t]);
        atomicAdd(&q1g[t], qp[t] + qp[104 + t]);
    }
}

// a = gamma*rsqrt(var+eps); c = beta - mu*a
__global__ void bn_fin_kernel(const float* __restrict__ s, const float* __restrict__ q,
                              const float* __restrict__ gamma, const float* __restrict__ beta,
                              float* __restrict__ a, float* __restrict__ c, int dim) {
    int j = threadIdx.x;
    if (j >= dim) return;
    float inv_n = 1.0f / (float)N_NODES;
    float mu = s[j] * inv_n;
    float var = q[j] * inv_n - mu * mu;
    float rs = rsqrtf(var + BN_EPS);
    float av = gamma[j] * rs;
    a[j] = av;
    c[j] = beta[j] - mu * av;
}

// ---------------------------------------------------------------------------
// gemm2: z = relu(y1*a1+c1); y2 = z @ W2 + b2; BN sums register-accumulated.
// block = 256 = 4 waves, j = lane (lanes 50..63 idle), 16 nodes per wave
// ---------------------------------------------------------------------------
#define G2N 64
__global__ __launch_bounds__(256) void gemm2_new_kernel(
    const float* __restrict__ y1, const float* __restrict__ a1, const float* __restrict__ c1,
    const float* __restrict__ W2, const float* __restrict__ b2,
    float* __restrict__ y2, float* __restrict__ s2g, float* __restrict__ q2g) {
    __shared__ float sz[G2N * D2];      // 25.6 KB
    __shared__ float sW[D2 * D];        // 20 KB
    __shared__ float sb[D];
    __shared__ float sa[D2], sc[D2];
    __shared__ float sp[4 * 52], qp[4 * 52];
    int t = threadIdx.x, n0 = blockIdx.x * G2N;
    for (int i = t; i < D2 * D; i += 256) sW[i] = W2[i];
    for (int i = t; i < D2; i += 256) { sa[i] = a1[i]; sc[i] = c1[i]; }
    for (int i = t; i < D; i += 256) sb[i] = b2[i];
    __syncthreads();
    for (int i = t; i < G2N * D2; i += 256) {
        int g = n0 * D2 + i;
        int dd = i % D2;
        float z = 0.0f;
        if (g < N_NODES * D2) z = fmaxf(y1[g] * sa[dd] + sc[dd], 0.0f);
        sz[i] = z;
    }
    __syncthreads();
    int j = t & 63, wv = t >> 6;
    if (j < D) {
        float s = 0.0f, q = 0.0f;
        for (int n = wv * 16; n < wv * 16 + 16; n++) {
            int g = n0 + n;
            if (g >= N_NODES) break;
            const float* r = &sz[n * D2];
            float v = sb[j];
#pragma unroll
            for (int d = 0; d < D2; d++) v += r[d] * sW[d * D + j];
            y2[(size_t)g * D + j] = v;
            s += v;
            q += v * v;
        }
        sp[wv * 52 + j] = s;
        qp[wv * 52 + j] = q;
    }
    __syncthreads();
    if (t < D) {
        atomicAdd(&s2g[t], sp[t] + sp[52 + t] + sp[104 + t] + sp[156 + t]);
        atomicAdd(&q2g[t], qp[t] + qp[52 + t] + qp[104 + t] + qp[156 + t]);
    }
}

// h = relu(y2*a2+c2)
__global__ void apply2_kernel(const float* __restrict__ y2, const float* __restrict__ a2,
                              const float* __restrict__ c2, float* __restrict__ h) {
    int t = blockIdx.x * blockDim.x + threadIdx.x;
    if (t >= N_NODES * D) return;
    int j = t % D;
    h[t] = fmaxf(y2[t] * a2[j] + c2[j], 0.0f);
}

// ---------------------------------------------------------------------------
// prediction head: out = h @ pred_W + pred_b
// block = 256: j = t%112, grp = t/112 (grps 0,1 -> 32 nodes each; 32 idle)
// ---------------------------------------------------------------------------
#define PN 64
__global__ __launch_bounds__(256) void pred_kernel(
    const float* __restrict__ h, const float* __restrict__ pW,
    const float* __restrict__ pb, float* __restrict__ out) {
    __shared__ float sh[PN * D];        // 12.8 KB
    __shared__ float sW[D * NTASK];     // 22.4 KB
    __shared__ float sb[NTASK];
    int t = threadIdx.x, n0 = blockIdx.x * PN;
    for (int i = t; i < D * NTASK; i += 256) sW[i] = pW[i];
    for (int i = t; i < NTASK; i += 256) sb[i] = pb[i];
    for (int i = t; i < PN * D; i += 256) {
        int g = n0 * D + i;
        sh[i] = (g < N_NODES * D) ? h[g] : 0.0f;
    }
    __syncthreads();
    int j = t % NTASK, grp = t / NTASK;
    if (grp < 2) {
        for (int n = grp * 32; n < grp * 32 + 32; n++) {
            int g = n0 + n;
            if (g >= N_NODES) break;
            const float* r = &sh[n * D];
            float v = sb[j];
#pragma unroll
            for (int d = 0; d < D; d++) v += r[d] * sW[d * NTASK + j];
            out[(size_t)g * NTASK + j] = v;
        }
    }
}

// ---------------------------------------------------------------------------
// Fallback path (R1-proven): atomic scatter + fused gemm1
// ---------------------------------------------------------------------------
__global__ void deg_kernel(const int* __restrict__ dst, float* __restrict__ invd) {
    int e = blockIdx.x * blockDim.x + threadIdx.x;
    if (e < N_EDGES) atomicAdd(&invd[dst[e]], 1.0f);
}

__global__ void invd_fin_kernel(float* __restrict__ invd) {
    int n = blockIdx.x * blockDim.x + threadIdx.x;
    if (n >= N_NODES) return;
    float dg = invd[n];
    invd[n] = (dg > 0.0f) ? (1.0f / dg) : 0.0f;
}

__global__ void scatter_kernel(const int* __restrict__ src, const int* __restrict__ dst,
                               const float* __restrict__ ef, const float* __restrict__ eW,
                               const float* __restrict__ eb, const float* __restrict__ h,
                               float* __restrict__ agg) {
    __shared__ float sW[IN_DIM * D];
    __shared__ float sb[D];
    for (int i = threadIdx.x; i < IN_DIM * D; i += blockDim.x) sW[i] = eW[i];
    for (int i = threadIdx.x; i < D; i += blockDim.x) sb[i] = eb[i];
    __syncthreads();
    int t = blockIdx.x * blockDim.x + threadIdx.x;
    if (t >= N_EDGES * D) return;
    int e = t / D, d = t % D;
    int s = src[e], dn = dst[e];
    float v = sb[d];
#pragma unroll
    for (int k = 0; k < IN_DIM; k++) v += ef[e * IN_DIM + k] * sW[k * D + d];
    v += h[s * D + d];
    atomicAdd(&agg[dn * D + d], v);
}

// fallback: combine inline then gemm1 (register BN stats like the new kernel)
__global__ __launch_bounds__(256) void gemm1_fb_kernel(
    const float* __restrict__ h, const float* __restrict__ agg, const float* __restrict__ invd,
    const float* __restrict__ W1, const float* __restrict__ b1, const float* __restrict__ epsArr,
    int layer, float* __restrict__ y1, float* __restrict__ s1g, float* __restrict__ q1g) {
    __shared__ float sh[G1N * D];
    __shared__ float sW[D * D2];
    __shared__ float sb[D2];
    __shared__ float sp[2 * 104], qp[2 * 104];
    float epsv = 1.0f + epsArr[layer];
    int t = threadIdx.x, n0 = blockIdx.x * G1N;
    for (int i = t; i < D * D2; i += 256) sW[i] = W1[i];
    for (int i = t; i < D2; i += 256) sb[i] = b1[i];
    for (int i = t; i < G1N * D; i += 256) {
        int n = i / D, d = i % D;
        int g = n0 + n;
        sh[i] = (g < N_NODES) ? (epsv * h[(size_t)g * D + d] + agg[(size_t)g * D + d] * invd[g]) : 0.0f;
    }
    __syncthreads();
    int j = t % D2, grp = t / D2;
    if (grp < 2) {
        float s = 0.0f, q = 0.0f;
        for (int n = grp * 32; n < grp * 32 + 32; n++) {
            int g = n0 + n;
            if (g >= N_NODES) break;
            const float* r = &sh[n * D];
            float v = sb[j];
#pragma unroll
            for (int d = 0; d < D; d++) v += r[d] * sW[d * D2 + j];
            y1[(size_t)g * D2 + j] = v;
            s += v;
            q += v * v;
        }
        sp[grp * 104 + j] = s;
        qp[grp * 104 + j] = q;
    }
    __syncthreads();
    if (t < D2) {
        atomicAdd(&s1g[t], sp[t] + sp[104 + t]);
        atomicAdd(&q1g[t], qp[t] + qp[104 + t]);
    }
}

// ---------------------------------------------------------------------------
extern "C" void kernel_launch(void* const* d_in, const int* in_sizes, int n_in,
                              void* d_out, int out_size, void* d_ws, size_t ws_size,
                              hipStream_t stream) {
    const int*   src        = (const int*)d_in[0];
    const int*   dst        = (const int*)d_in[1];
    const float* node_feats = (const float*)d_in[2];
    const float* edge_feats = (const float*)d_in[3];
    const float* node_W     = (const float*)d_in[4];
    const float* node_b     = (const float*)d_in[5];
    const float* edge_W     = (const float*)d_in[6];
    const float* edge_b     = (const float*)d_in[7];
    const float* epsArr     = (const float*)d_in[8];
    const float* W1         = (const float*)d_in[9];
    const float* b1         = (const float*)d_in[10];
    const float* g1         = (const float*)d_in[11];
    const float* be1        = (const float*)d_in[12];
    const float* W2         = (const float*)d_in[13];
    const float* b2         = (const float*)d_in[14];
    const float* g2         = (const float*)d_in[15];
    const float* be2        = (const float*)d_in[16];
    const float* pred_W     = (const float*)d_in[17];
    const float* pred_b     = (const float*)d_in[18];
    float* out = (float*)d_out;

    // ---- workspace layout (shared prefix between both paths) ----
    float* ws   = (float*)d_ws;
    float* h    = ws;                               // 5,000,000 f
    float* tmp  = h + (size_t)N_NODES * D;          // 5,000,000 f (hnew / y2 / agg)
    float* invd = tmp + (size_t)N_NODES * D;        // 100,000 f
    float* st   = invd + N_NODES;                   // 768 f
    float* s1 = st, *q1 = st + 128, *s2 = st + 256, *q2 = st + 320;
    float* a1 = st + 384, *c1 = st + 512, *a2 = st + 640, *c2 = st + 704;
    // CSR arrays (primary path only)
    int* degi   = (int*)(st + 768);                 // 100,000
    int* off    = degi + N_NODES;                   // 100,001
    int* cursor = off + N_NODES + 1;                // 100,000
    int* bsum   = cursor + N_NODES;                 // NBLK
    int* bpre   = bsum + NBLK;                      // NBLK
    int2* adj   = (int2*)(bpre + NBLK + 1);         // 1,600,000 int2
    size_t needed = (size_t)((char*)(adj + N_EDGES) - (char*)d_ws);
    float* y1 = out;    // 40 MB, fully overwritten by pred at the end

    node_enc_kernel<<<(N_NODES + NE_NODES - 1) / NE_NODES, 256, 0, stream>>>(
        node_feats, node_W, node_b, h);

    if (ws_size >= needed) {
        // ================= primary: CSR + gather =================
        hipMemsetAsync(degi, 0, N_NODES * sizeof(int), stream);
        k_deg<<<(N_EDGES + 255) / 256, 256, 0, stream>>>(dst, degi);
        k_bsum<<<NBLK, 256, 0, stream>>>(degi, bsum);
        k_bscan<<<1, 512, 0, stream>>>(bsum, bpre);
        k_off<<<NBLK, 256, 0, stream>>>(degi, bpre, off, cursor, invd);
        k_fill<<<(N_EDGES + 255) / 256, 256, 0, stream>>>(src, dst, cursor, adj);

        for (int layer = 0; layer < 2; layer++) {
            hipMemsetAsync(st, 0, 384 * sizeof(float), stream);
            gather_kernel<<<(N_NODES + 3) / 4, 256, 0, stream>>>(
                off, adj, edge_feats, edge_W, edge_b, h, invd, epsArr, layer, tmp);
            gemm1_new_kernel<<<(N_NODES + G1N - 1) / G1N, 256, 0, stream>>>(
                tmp, W1 + layer * D * D2, b1 + layer * D2, y1, s1, q1);
            bn_fin_kernel<<<1, 128, 0, stream>>>(s1, q1, g1 + layer * D2, be1 + layer * D2, a1, c1, D2);
            gemm2_new_kernel<<<(N_NODES + G2N - 1) / G2N, 256, 0, stream>>>(
                y1, a1, c1, W2 + layer * D2 * D, b2 + layer * D, tmp, s2, q2);
            bn_fin_kernel<<<1, 128, 0, stream>>>(s2, q2, g2 + layer * D, be2 + layer * D, a2, c2, D);
            apply2_kernel<<<(N_NODES * D + 255) / 256, 256, 0, stream>>>(tmp, a2, c2, h);
        }
    } else {
        // ================= fallback: R1 atomic scatter =================
        float* agg = tmp;
        hipMemsetAsync(invd, 0, N_NODES * sizeof(float), stream);
        deg_kernel<<<(N_EDGES + 255) / 256, 256, 0, stream>>>(dst, invd);
        invd_fin_kernel<<<(N_NODES + 255) / 256, 256, 0, stream>>>(invd);
        for (int layer = 0; layer < 2; layer++) {
            hipMemsetAsync(agg, 0, (size_t)N_NODES * D * sizeof(float), stream);
            hipMemsetAsync(st, 0, 384 * sizeof(float), stream);
            scatter_kernel<<<(N_EDGES * D + 255) / 256, 256, 0, stream>>>(
                src, dst, edge_feats, edge_W, edge_b, h, agg);
            gemm1_fb_kernel<<<(N_NODES + G1N - 1) / G1N, 256, 0, stream>>>(
                h, agg, invd, W1 + layer * D * D2, b1 + layer * D2, epsArr, layer, y1, s1, q1);
            bn_fin_kernel<<<1, 128, 0, stream>>>(s1, q1, g1 + layer * D2, be1 + layer * D2, a1, c1, D2);
            gemm2_new_kernel<<<(N_NODES + G2N - 1) / G2N, 256, 0, stream>>>(
                y1, a1, c1, W2 + layer * D2 * D, b2 + layer * D, agg, s2, q2);
            bn_fin_kernel<<<1, 128, 0, stream>>>(s2, q2, g2 + layer * D, be2 + layer * D, a2, c2, D);
            apply2_kernel<<<(N_NODES * D + 255) / 256, 256, 0, stream>>>(agg, a2, c2, h);
        }
    }
    pred_kernel<<<(N_NODES + PN - 1) / PN, 256, 0, stream>>>(h, pred_W, pred_b, out);
}